// Round 1
// baseline (3563.435 us; speedup 1.0000x reference)
//
#include <hip/hip_runtime.h>
#include <math.h>

// ---------------------------------------------------------------------------
// RITS forward, round 5: pair-split recurrence. 256 blocks x 1024 threads.
// Each PAIR of blocks (bid, bid+128) processes the same 2 batch rows; each
// block owns half of the hidden units (128 of 256) and therefore streams only
// HALF of the gate weights (512 KB instead of 1 MB per step) plus half of
// tdh/hist. One 1.5 KB cross-block exchange per step (decayed-h half packed
// f16 + x_h f32 K-partials) via device-scope atomics + flag handshake,
// double-buffered on step parity. All 256 CUs active; per-CU L2 streaming
// (the measured bottleneck) drops from ~1.22 MB/step to ~0.68 MB/step.
// B=256, L=256, D=128, H=256.
// ---------------------------------------------------------------------------

namespace {
constexpr int Bn = 256, Ln = 256, Dn = 128, Hn = 256;
constexpr long LD = (long)Ln * Dn;  // 32768

// ws byte offsets
constexpr int OFF_LOSS  = 0;
constexpr int OFF_DEN   = 256;      // 256 f32
constexpr int OFF_BIASG = 2048;     // 1024 f32 [jj][q]
constexpr int OFF_WG    = 8192;     // 262144 dw: [kp<128][jj<256][8]
                                    //   dw 0..3 = W_ih q0..3 pair kp, 4..7 = W_hh
constexpr int OFF_HISTP = 1056768;  // 16384 dw [kp<128][d<128]
constexpr int OFF_TDHP  = 1122304;  // 16384 dw [kp<64][h<256]
constexpr int OFF_WFP   = 1187840;  // 8192 dw  [kp<64][d<128] (diag=0)
constexpr int OFF_WCP   = 1220608;  // 16384 dw [kp<128][d<128]
constexpr int OFF_EXCH  = 1310720;  // 128 pair * 2 s * 2 parity * 1536 B
constexpr int OFF_FLAG  = 2097152;  // 256 flags * 64 B = 16384 B
}  // namespace

typedef _Float16 h2f __attribute__((ext_vector_type(2)));
typedef unsigned int uint32;
typedef unsigned long long uint64;

__device__ __forceinline__ float fdot2(uint32 a, uint32 b, float c) {
  return __builtin_amdgcn_fdot2(__builtin_bit_cast(h2f, a),
                                __builtin_bit_cast(h2f, b), c, false);
}
__device__ __forceinline__ uint32 packf16(float a, float b) {
  h2f p; p[0] = (_Float16)a; p[1] = (_Float16)b;
  return __builtin_bit_cast(uint32, p);
}
__device__ __forceinline__ unsigned short f16u(float a) {
  _Float16 h = (_Float16)a; return __builtin_bit_cast(unsigned short, h);
}

// ======================= K1: repack + biases + denom ========================
__global__ void rits_prep(const float* __restrict__ td_h_W,
                          const float* __restrict__ hist_W,
                          const float* __restrict__ feat_W,
                          const float* __restrict__ wc_W,
                          const float* __restrict__ W_ih,
                          const float* __restrict__ W_hh,
                          const float* __restrict__ b_ih,
                          const float* __restrict__ b_hh,
                          const float* __restrict__ evalm,
                          char* __restrict__ wsb) {
  const int blk = blockIdx.x, tid = threadIdx.x;
  if (blk < 1248) {
    int idx = blk * 256 + tid;
    if (idx < 262144) {  // wg
      int kp = idx >> 11, rem = idx & 2047, jj = rem >> 3, s8 = rem & 7;
      const float* src = (s8 < 4) ? W_ih : W_hh;
      int q = s8 & 3;
      const float* row = src + (size_t)(q * 256 + jj) * 256 + 2 * kp;
      ((uint32*)(wsb + OFF_WG))[idx] = packf16(row[0], row[1]);
    } else if (idx < 278528) {  // histP
      int i2 = idx - 262144, kp = i2 >> 7, d = i2 & 127;
      ((uint32*)(wsb + OFF_HISTP))[i2] =
          packf16(hist_W[d * 256 + 2 * kp], hist_W[d * 256 + 2 * kp + 1]);
    } else if (idx < 294912) {  // tdhP
      int i2 = idx - 278528, kp = i2 >> 8, h = i2 & 255;
      ((uint32*)(wsb + OFF_TDHP))[i2] =
          packf16(td_h_W[h * 128 + 2 * kp], td_h_W[h * 128 + 2 * kp + 1]);
    } else if (idx < 303104) {  // wfP: [kp<64][d<128], Wf[d][k], diag=0
      int i2 = idx - 294912, kp = i2 >> 7, d = i2 & 127;
      float a = (2 * kp == d) ? 0.f : feat_W[d * 128 + 2 * kp];
      float b = (2 * kp + 1 == d) ? 0.f : feat_W[d * 128 + 2 * kp + 1];
      ((uint32*)(wsb + OFF_WFP))[i2] = packf16(a, b);
    } else if (idx < 319488) {  // wcP
      int i2 = idx - 303104, kp = i2 >> 7, d = i2 & 127;
      ((uint32*)(wsb + OFF_WCP))[i2] =
          packf16(wc_W[d * 256 + 2 * kp], wc_W[d * 256 + 2 * kp + 1]);
    }
  } else if (blk < 1252) {  // biasg
    int i = (blk - 1248) * 256 + tid;
    int jj = i >> 2, q = i & 3;
    ((float*)(wsb + OFF_BIASG))[jj * 4 + q] =
        b_ih[q * 256 + jj] + b_hh[q * 256 + jj];
    if (blk == 1248 && tid == 0) *((float*)(wsb + OFF_LOSS)) = 0.f;
  } else if (blk < 1508) {  // denom per t
    int t = blk - 1252;
    __shared__ float red[256];
    int d = tid & 127, g = tid >> 7;
    float s = 0.f;
    for (int b = g; b < 256; b += 2) s += evalm[(size_t)b * LD + t * 128 + d];
    red[tid] = s;
    __syncthreads();
    for (int o = 128; o > 0; o >>= 1) {
      if (tid < o) red[tid] += red[tid + o];
      __syncthreads();
    }
    if (tid == 0) ((float*)(wsb + OFF_DEN))[t] = red[0] + 1e-5f;
  } else {  // blk == 1508: zero exchange flags (required each launch/replay)
    for (int i = tid; i < 4096; i += 256) ((uint32*)(wsb + OFF_FLAG))[i] = 0u;
  }
}

// ========================== K2: recurrent blocks ============================
__global__ __launch_bounds__(1024, 4) void rits_rec(
    const float* __restrict__ values, const float* __restrict__ masks,
    const float* __restrict__ deltas, const float* __restrict__ evalm,
    const float* __restrict__ td_h_b, const float* __restrict__ td_x_w,
    const float* __restrict__ td_x_b, const float* __restrict__ hist_b,
    const float* __restrict__ feat_b, const float* __restrict__ wc_b,
    char* __restrict__ wsb, float* __restrict__ outp) {
  __shared__ __align__(16) float scratch[8448];  // shared partial region
  __shared__ float den_s[256], bg_s[512], tdhb_s[128];
  __shared__ float txw_s[128], txb_s[128], hb_s[128], fb_s[128], wcb_s[128];
  __shared__ float hf[2][128], cst[2][128];          // own h-half, both rows
  __shared__ float xs[2][128], ms[2][128], es[2][128];
  __shared__ float xhp[2][2][128];                   // [K-half][r][d] partials
  __shared__ float xh_s[2][128], al_s[2][128];
  __shared__ __align__(8) unsigned short hdU16[128 * 4];  // full hd pairs
  __shared__ __align__(8) unsigned short cmU16[128 * 4];  // [c_c|m] pairs
  __shared__ __align__(8) unsigned short xcU16[64 * 4];   // x_c pairs
  __shared__ uint32 drP[64 * 2];    // deltas pairs [kp][r]
  __shared__ uint32 gxmP[128 * 2];  // [gamma_x|m] pairs [kp][r]

  const int tid = threadIdx.x;
  const int bid = blockIdx.x;
  const int sh = bid >> 7;          // which half of h/jj this block owns
  const int pair = bid & 127;
  const size_t b0 = (size_t)pair * 2;
  const uint32* hdU32 = (const uint32*)hdU16;
  const uint32* cmU32 = (const uint32*)cmU16;
  const uint32* xcU32 = (const uint32*)xcU16;
  const uint32* wg = (const uint32*)(wsb + OFF_WG);
  const uint4* histP4 = (const uint4*)(wsb + OFF_HISTP);
  const uint4* tdhP4 = (const uint4*)(wsb + OFF_TDHP);
  const uint4* wfP4 = (const uint4*)(wsb + OFF_WFP);
  const uint4* wcP4 = (const uint4*)(wsb + OFF_WCP);
  char* exch = wsb + OFF_EXCH;
  unsigned int* myf = (unsigned int*)(wsb + OFF_FLAG + ((pair << 1) | sh) * 64);
  unsigned int* pf  = (unsigned int*)(wsb + OFF_FLAG + ((pair << 1) | (sh ^ 1)) * 64);

  // -------- preload / init --------
  if (tid < 512) bg_s[tid] = ((const float*)(wsb + OFF_BIASG))[sh * 512 + tid];
  else if (tid < 768) den_s[tid - 512] = ((const float*)(wsb + OFF_DEN))[tid - 512];
  else if (tid < 896) tdhb_s[tid - 768] = td_h_b[(sh << 7) + (tid - 768)];
  else txw_s[tid - 896] = td_x_w[tid - 896];
  if (tid < 128) txb_s[tid] = td_x_b[tid];
  else if (tid < 256) hb_s[tid - 128] = hist_b[tid - 128];
  else if (tid < 384) fb_s[tid - 256] = feat_b[tid - 256];
  else if (tid < 512) wcb_s[tid - 384] = wc_b[tid - 384];
  else {
    int i = tid - 512;
    if (i < 256) ((float*)hf)[i] = 0.f;
    else ((float*)cst)[i - 256] = 0.f;
  }
  __syncthreads();

  float lacc = 0.f;
  for (int t = 0; t < Ln; ++t) {
    const size_t base = b0 * LD + (size_t)t * 128;
    uint64* myp = (uint64*)(exch + ((((pair << 1) | sh) << 1) | (t & 1)) * 1536);
    uint64* pp  = (uint64*)(exch + ((((pair << 1) | (sh ^ 1)) << 1) | (t & 1)) * 1536);

    // ---- A: stage inputs; gamma_x & m pairs ----
    if (tid < 256) {
      int d = tid & 127, r = tid >> 7;
      size_t gi = base + (size_t)r * LD + d;
      xs[r][d] = values[gi];
      ms[r][d] = masks[gi];
      es[r][d] = evalm[gi];
    } else if (tid < 512) {
      int i = tid - 256, kp = i & 127, r = i >> 7;
      size_t gb = base + (size_t)r * LD;
      if (kp < 64) {
        float d0v = deltas[gb + 2 * kp], d1v = deltas[gb + 2 * kp + 1];
        drP[kp * 2 + r] = packf16(d0v, d1v);
        float g0 = __expf(-fmaxf(fmaf(d0v, txw_s[2 * kp], txb_s[2 * kp]), 0.f));
        float g1 = __expf(-fmaxf(fmaf(d1v, txw_s[2 * kp + 1], txb_s[2 * kp + 1]), 0.f));
        gxmP[kp * 2 + r] = packf16(g0, g1);
      } else {
        int k2 = kp - 64;
        gxmP[kp * 2 + r] = packf16(masks[gb + 2 * k2], masks[gb + 2 * k2 + 1]);
      }
    }
    __syncthreads();

    // ---- B: gamma_h partials own-half (256 thr) | alpha partials (512 thr) --
    if (tid < 256) {  // g_loc<32 (own h-quads), r, kq<4 (16 kp each)
      int g = tid & 31, r = (tid >> 5) & 1, kq = tid >> 6;
      int gg = (sh << 5) + g;
      float4 a = {0.f, 0.f, 0.f, 0.f};
#pragma unroll 4
      for (int i = 0; i < 16; ++i) {
        int kp = kq * 16 + i;
        uint4 w = tdhP4[kp * 64 + gg];
        uint32 dr = drP[kp * 2 + r];
        a.x = fdot2(dr, w.x, a.x); a.y = fdot2(dr, w.y, a.y);
        a.z = fdot2(dr, w.z, a.z); a.w = fdot2(dr, w.w, a.w);
      }
      ((float4*)(scratch + (kq * 2 + r) * 132))[g] = a;
    } else if (tid < 768) {  // alpha (full, redundant): g=d4, r, kq<8 (16 kp)
      int i0 = tid - 256, g = i0 & 31, r = (i0 >> 5) & 1, kq = i0 >> 6;
      float4 a = {0.f, 0.f, 0.f, 0.f};
#pragma unroll 4
      for (int i = 0; i < 16; ++i) {
        int kp = kq * 16 + i;
        uint4 w = wcP4[kp * 32 + g];
        uint32 gm = gxmP[kp * 2 + r];
        a.x = fdot2(gm, w.x, a.x); a.y = fdot2(gm, w.y, a.y);
        a.z = fdot2(gm, w.z, a.z); a.w = fdot2(gm, w.w, a.w);
      }
      ((float4*)(scratch + 1056 + (kq * 2 + r) * 132))[g] = a;
    }
    __syncthreads();

    // ---- C: reduce gamma_h -> own hd pairs ; reduce alpha ----
    if (tid < 256) {
      int hl = tid & 127, r = tid >> 7;
      float ssum = tdhb_s[hl];
#pragma unroll
      for (int kq = 0; kq < 4; ++kq) ssum += scratch[(kq * 2 + r) * 132 + hl];
      float hd = hf[r][hl] * __expf(-fmaxf(ssum, 0.f));
      int hg = (sh << 7) | hl;
      hdU16[(hg >> 1) * 4 + 2 * r + (hg & 1)] = f16u(hd);
    } else if (tid >= 512 && tid < 768) {
      int i0 = tid - 512, d = i0 & 127, r = i0 >> 7;
      float ssum = wcb_s[d];
#pragma unroll
      for (int kq = 0; kq < 8; ++kq) ssum += scratch[1056 + (kq * 2 + r) * 132 + d];
      al_s[r][d] = ssum;
    }
    __syncthreads();

    // ---- D: x_h partials over OWN K-half (512 thr) | post hd payload ----
    if (tid < 512) {
      int g = tid & 31, r = (tid >> 5) & 1, kq = tid >> 6;
      float4 a = {0.f, 0.f, 0.f, 0.f};
#pragma unroll 4
      for (int i = 0; i < 8; ++i) {
        int kp = (sh << 6) + kq * 8 + i;
        uint4 w = histP4[kp * 32 + g];
        uint32 hd = hdU32[kp * 2 + r];
        a.x = fdot2(hd, w.x, a.x); a.y = fdot2(hd, w.y, a.y);
        a.z = fdot2(hd, w.z, a.z); a.w = fdot2(hd, w.w, a.w);
      }
      ((float4*)(scratch + (kq * 2 + r) * 132))[g] = a;
    } else if (tid < 576) {  // hd payload: own 64 u64 (= 64 kp pairs)
      int i = tid - 512;
      uint64 v = ((const uint64*)hdU16)[(sh << 6) + i];
      __hip_atomic_store(myp + i, v, __ATOMIC_RELAXED, __HIP_MEMORY_SCOPE_AGENT);
    }
    __syncthreads();

    // ---- E0: reduce own x_h partial; post as payload ----
    if (tid < 256) {
      int d = tid & 127, r = tid >> 7;
      float xo = 0.f;
#pragma unroll
      for (int kq = 0; kq < 8; ++kq) xo += scratch[(kq * 2 + r) * 132 + d];
      xhp[sh][r][d] = xo;
      __hip_atomic_store((uint32*)myp + 128 + (r << 7) + d,
                         __builtin_bit_cast(uint32, xo),
                         __ATOMIC_RELAXED, __HIP_MEMORY_SCOPE_AGENT);
    }
    __syncthreads();  // drains vmcnt: all payload stores device-visible

    // ---- handshake: release own flag, spin on partner ----
    if (tid == 0) {
      __hip_atomic_store(myf, (unsigned)(t + 1), __ATOMIC_RELEASE,
                         __HIP_MEMORY_SCOPE_AGENT);
      unsigned guard = 0;
      while (__hip_atomic_load(pf, __ATOMIC_ACQUIRE,
                               __HIP_MEMORY_SCOPE_AGENT) < (unsigned)(t + 1)) {
        if (++guard > (1u << 22)) break;  // bounded: avoid hard hang
      }
    }
    __syncthreads();

    // ---- load partner payload: hd other-half + x_h other K-partial ----
    if (tid < 192) {
      uint64 v = __hip_atomic_load(pp + tid, __ATOMIC_RELAXED,
                                   __HIP_MEMORY_SCOPE_AGENT);
      if (tid < 64) {
        ((uint64*)hdU16)[((sh ^ 1) << 6) + tid] = v;
      } else {
        int j = tid - 64;  // 0..127 -> (r, d pair)
        int r = j >> 6, d2 = (j & 63) << 1;
        xhp[sh ^ 1][r][d2] = __builtin_bit_cast(float, (uint32)v);
        xhp[sh ^ 1][r][d2 + 1] = __builtin_bit_cast(float, (uint32)(v >> 32));
      }
    }
    __syncthreads();

    // ---- E1: x_h (fixed sum order => bitwise-identical across pair), x_c ---
    if (tid < 256) {
      int d = tid & 127, r = tid >> 7;
      float xh = xhp[0][r][d] + xhp[1][r][d] + hb_s[d];
      xh_s[r][d] = xh;
      float mm = ms[r][d];
      float xc = mm * xs[r][d] + (1.f - mm) * xh;
      xcU16[(d >> 1) * 4 + 2 * r + (d & 1)] = f16u(xc);
    }
    __syncthreads();

    // ---- F: z partials (full, redundant; 512 thr) ----
    if (tid < 512) {
      int g = tid & 31, r = (tid >> 5) & 1, kq = tid >> 6;
      float4 a = {0.f, 0.f, 0.f, 0.f};
#pragma unroll 4
      for (int i = 0; i < 8; ++i) {
        int kp = kq * 8 + i;
        uint4 w = wfP4[kp * 32 + g];
        uint32 xc = xcU32[kp * 2 + r];
        a.x = fdot2(xc, w.x, a.x); a.y = fdot2(xc, w.y, a.y);
        a.z = fdot2(xc, w.z, a.z); a.w = fdot2(xc, w.w, a.w);
      }
      ((float4*)(scratch + (kq * 2 + r) * 132))[g] = a;
    }
    __syncthreads();

    // ---- G: c_h, c_c; out+loss only for own row (r==sh); pack [c_c|m] ----
    if (tid < 256) {
      int d = tid & 127, r = tid >> 7;
      float z = fb_s[d];
#pragma unroll
      for (int kq = 0; kq < 8; ++kq) z += scratch[(kq * 2 + r) * 132 + d];
      float a = al_s[r][d], xh = xh_s[r][d];
      float ch = a * z + (1.f - a) * xh;
      float mm = ms[r][d], xv = xs[r][d];
      float cc = mm * xv + (1.f - mm) * ch;
      if (r == sh) {
        outp[base + (size_t)r * LD + d] = cc;
        lacc += (1.f - mm) * fabsf(ch - xv) * es[r][d] / den_s[t];
      }
      cmU16[(d >> 1) * 4 + 2 * r + (d & 1)] = f16u(cc);
      cmU16[(64 + (d >> 1)) * 4 + 2 * r + (d & 1)] = f16u(mm);
    }
    __syncthreads();

    // ---- H: gate partials, OWN jj-half: jj=tid&127, kq=tid>>7 (16 kp each) --
    {
      int jj = tid & 127, kq = tid >> 7;
      int jg = (sh << 7) | jj;
      int kp0 = kq * 16;
      const uint4* wp = (const uint4*)(wg + ((size_t)kp0 * 256 + jg) * 8);
      float a00 = 0, a01 = 0, a02 = 0, a03 = 0;
      float a10 = 0, a11 = 0, a12 = 0, a13 = 0;
#pragma unroll 4
      for (int i = 0; i < 16; ++i) {
        int kp = kp0 + i;
        uint4 wv = wp[0];
        uint4 wh = wp[1];
        wp += 512;
        uint32 c0 = cmU32[kp * 2 + 0], c1 = cmU32[kp * 2 + 1];
        uint32 h0 = hdU32[kp * 2 + 0], h1 = hdU32[kp * 2 + 1];
        a00 = fdot2(c0, wv.x, a00); a01 = fdot2(c0, wv.y, a01);
        a02 = fdot2(c0, wv.z, a02); a03 = fdot2(c0, wv.w, a03);
        a10 = fdot2(c1, wv.x, a10); a11 = fdot2(c1, wv.y, a11);
        a12 = fdot2(c1, wv.z, a12); a13 = fdot2(c1, wv.w, a13);
        a00 = fdot2(h0, wh.x, a00); a01 = fdot2(h0, wh.y, a01);
        a02 = fdot2(h0, wh.z, a02); a03 = fdot2(h0, wh.w, a03);
        a10 = fdot2(h1, wh.x, a10); a11 = fdot2(h1, wh.y, a11);
        a12 = fdot2(h1, wh.z, a12); a13 = fdot2(h1, wh.w, a13);
      }
      // pg[slot*132 + jj], slot = kq*8 + r*4 + q (conflict-free both ways)
      float* pg = scratch;
      pg[(kq * 8 + 0) * 132 + jj] = a00; pg[(kq * 8 + 1) * 132 + jj] = a01;
      pg[(kq * 8 + 2) * 132 + jj] = a02; pg[(kq * 8 + 3) * 132 + jj] = a03;
      pg[(kq * 8 + 4) * 132 + jj] = a10; pg[(kq * 8 + 5) * 132 + jj] = a11;
      pg[(kq * 8 + 6) * 132 + jj] = a12; pg[(kq * 8 + 7) * 132 + jj] = a13;
    }
    __syncthreads();

    // ---- I: reduce gates + LSTM (own h-half, both rows) ----
    if (tid < 256) {
      int jj = tid & 127, r = tid >> 7;
      float g0 = bg_s[jj * 4 + 0], g1 = bg_s[jj * 4 + 1];
      float g2 = bg_s[jj * 4 + 2], g3 = bg_s[jj * 4 + 3];
#pragma unroll
      for (int kq = 0; kq < 8; ++kq) {
        int bix = (kq * 8 + r * 4) * 132 + jj;
        g0 += scratch[bix]; g1 += scratch[bix + 132];
        g2 += scratch[bix + 264]; g3 += scratch[bix + 396];
      }
      float ig = 1.f / (1.f + __expf(-g0));
      float fg = 1.f / (1.f + __expf(-g1));
      float gg = tanhf(g2);
      float og = 1.f / (1.f + __expf(-g3));
      float c = fg * cst[r][jj] + ig * gg;
      cst[r][jj] = c;
      hf[r][jj] = og * tanhf(c);
    }
    __syncthreads();
  }

  // -------- loss reduce --------
  scratch[tid] = lacc;
  __syncthreads();
  for (int o = 512; o > 0; o >>= 1) {
    if (tid < o) scratch[tid] += scratch[tid + o];
    __syncthreads();
  }
  if (tid == 0) atomicAdd((float*)(wsb + OFF_LOSS), scratch[0]);
}

// ========================== K3: loss scalar =================================
__global__ void rits_fin(const char* __restrict__ wsb, float* __restrict__ outp) {
  if (threadIdx.x == 0 && blockIdx.x == 0)
    outp[(size_t)Bn * LD] = *((const float*)(wsb + OFF_LOSS));
}

// ============================== launcher ====================================
extern "C" void kernel_launch(void* const* d_in, const int* in_sizes, int n_in,
                              void* d_out, int out_size, void* d_ws,
                              size_t ws_size, hipStream_t stream) {
  const float* values = (const float*)d_in[0];
  const float* masks  = (const float*)d_in[1];
  const float* deltas = (const float*)d_in[2];
  const float* evalm  = (const float*)d_in[3];
  const float* td_h_W = (const float*)d_in[4];
  const float* td_h_b = (const float*)d_in[5];
  const float* td_x_w = (const float*)d_in[6];
  const float* td_x_b = (const float*)d_in[7];
  const float* hist_W = (const float*)d_in[8];
  const float* hist_b = (const float*)d_in[9];
  const float* feat_W = (const float*)d_in[10];
  const float* feat_b = (const float*)d_in[11];
  const float* wc_W   = (const float*)d_in[12];
  const float* wc_b   = (const float*)d_in[13];
  const float* W_ih   = (const float*)d_in[14];
  const float* W_hh   = (const float*)d_in[15];
  const float* b_ih   = (const float*)d_in[16];
  const float* b_hh   = (const float*)d_in[17];
  char* wsb = (char*)d_ws;
  float* outp = (float*)d_out;

  hipLaunchKernelGGL(rits_prep, dim3(1509), dim3(256), 0, stream, td_h_W,
                     hist_W, feat_W, wc_W, W_ih, W_hh, b_ih, b_hh, evalm, wsb);
  hipLaunchKernelGGL(rits_rec, dim3(256), dim3(1024), 0, stream, values, masks,
                     deltas, evalm, td_h_b, td_x_w, td_x_b, hist_b, feat_b,
                     wc_b, wsb, outp);
  hipLaunchKernelGGL(rits_fin, dim3(1), dim3(64), 0, stream, wsb, outp);
}